// Round 5
// baseline (207.337 us; speedup 1.0000x reference)
//
#include <hip/hip_runtime.h>

#define N_PTS 4096
#define B_SZ 4
#define C_IN 64
#define C_OUT 128
#define NS 9
#define KTOT (C_IN * NS)   // 576
#define RAD2 0.04f

typedef __attribute__((ext_vector_type(8))) short bf16x8;
typedef __attribute__((ext_vector_type(4))) float f32x4;

__device__ inline ushort f2bf(float f) {
    union { float f; unsigned u; } v; v.f = f;
    unsigned r = (v.u + 0x7FFF + ((v.u >> 16) & 1)) >> 16;   // RTNE
    return (ushort)r;
}

// ---------------- kernel 0: fused prep (wt | xt | pack-pcs), role by blockIdx ----
__global__ void __launch_bounds__(256) prep_kernel(
    const float* __restrict__ W, const float* __restrict__ x,
    const float* __restrict__ pcs,
    ushort* __restrict__ Wt, ushort* __restrict__ xT, float4* __restrict__ pp)
{
    __shared__ ushort tile[64][66];
    const int t = threadIdx.x;
    const int blk = blockIdx.x;
    if (blk < 288) {                       // ---- Wt [o][k], k = s*64+c ----
        int id = blk * 256 + t;
        int o = id / KTOT;
        int r = id - o * KTOT;
        int s = r >> 6, c = r & 63;
        Wt[id] = f2bf(W[o * KTOT + c * NS + s]);
    } else if (blk < 544) {                // ---- xT [b][n][c] bf16 ----
        int r = blk - 288;
        int b = r >> 6;
        int n0 = (r & 63) * 64;
        const float* xb = x + (size_t)b * C_IN * N_PTS;
        #pragma unroll
        for (int i = 0; i < 16; ++i) {
            int flat = i * 256 + t;
            int c = flat >> 6, n = flat & 63;
            tile[c][n] = f2bf(xb[(size_t)c * N_PTS + n0 + n]);
        }
        __syncthreads();
        ushort* xTb = xT + ((size_t)b * N_PTS + n0) * C_IN;
        #pragma unroll
        for (int i = 0; i < 16; ++i) {
            int flat = i * 256 + t;
            int n = flat >> 6, c = flat & 63;
            xTb[(size_t)n * C_IN + c] = tile[c][n];
        }
    } else {                               // ---- pack pcs -> {x,y,z,sq} ----
        int id = (blk - 544) * 256 + t;
        int b = id >> 12, n = id & (N_PTS - 1);
        const float* pb = pcs + (size_t)b * 3 * N_PTS;
        float px = pb[n], py = pb[N_PTS + n], pz = pb[2 * N_PTS + n];
        float sq = __fadd_rn(__fadd_rn(__fmul_rn(px, px), __fmul_rn(py, py)),
                             __fmul_rn(pz, pz));
        pp[id] = make_float4(px, py, pz, sq);
    }
}

// ---------------- kernel 1: ball query (verified) ----------------
__global__ void __launch_bounds__(256) ballq_kernel(const float4* __restrict__ pp,
                                                    int* __restrict__ idxT) {
    int wid = (blockIdx.x * 256 + threadIdx.x) >> 6;
    int lane = threadIdx.x & 63;
    int b = wid >> 12;
    int n = wid & (N_PTS - 1);
    const float4* pb = pp + (size_t)b * N_PTS;
    float4 c = pb[n];
    int* outb = idxT + (size_t)b * NS * N_PTS + n;
    int cnt = 0, first = -1;
    for (int c0 = 0; c0 < N_PTS; c0 += 256) {
        float4 q[4];
        #pragma unroll
        for (int j = 0; j < 4; ++j) q[j] = pb[c0 + j * 64 + lane];
        #pragma unroll
        for (int j = 0; j < 4; ++j) {
            int m = c0 + j * 64 + lane;
            float dot = __fadd_rn(__fadd_rn(__fmul_rn(c.x, q[j].x),
                                            __fmul_rn(c.y, q[j].y)),
                                  __fmul_rn(c.z, q[j].z));
            float d2 = __fsub_rn(__fadd_rn(c.w, q[j].w), __fmul_rn(2.0f, dot));
            bool hit = !(d2 > RAD2);
            unsigned long long mask = __ballot(hit);
            if (mask) {
                if (first < 0) first = c0 + j * 64 + __ffsll(mask) - 1;
                int pre = __popcll(mask & ((1ull << lane) - 1ull));
                if (hit) {
                    int slot = cnt + pre;
                    if (slot < NS) outb[slot * N_PTS] = m;
                }
                cnt += __popcll(mask);
                if (cnt >= NS) break;
            }
        }
        if (cnt >= NS) break;
    }
    if (lane >= cnt && lane < NS) outb[lane * N_PTS] = first;
}

// ---------------- kernel 2: spill-proof barrier-free gathered MFMA GEMM ----
// grid (256,2) x 4 waves; wave tile 32(o) x 32(n); s-loop unroll 3,
// per-iteration index loads -> bounded live set (~70 VGPR), no scratch.
__global__ void __launch_bounds__(256) conv_kernel(
    const ushort* __restrict__ xT, const ushort* __restrict__ Wt,
    const int* __restrict__ idxT, const float* __restrict__ bias,
    float* __restrict__ y)
{
    const int t = threadIdx.x;
    const int lane = t & 63;
    const int wid = t >> 6;
    const int b = blockIdx.x >> 6;
    const int gn0 = (blockIdx.x & 63) * 64;
    const int m0 = blockIdx.y * 64 + (wid >> 1) * 32;   // wave o-base
    const int n0 = gn0 + (wid & 1) * 32;                // wave n-base

    const int l15 = lane & 15;
    const int l4 = lane >> 4;                            // 0..3

    const int* ip = idxT + (size_t)b * NS * N_PTS + n0 + l15;
    const ushort* xTb = xT + (size_t)b * N_PTS * C_IN;
    const ushort* wp = Wt + (size_t)(m0 + l15) * KTOT;

    f32x4 acc[2][2];
    #pragma unroll
    for (int i = 0; i < 2; ++i)
        #pragma unroll
        for (int j = 0; j < 2; ++j)
            acc[i][j] = (f32x4){0.f, 0.f, 0.f, 0.f};

    #pragma unroll 3
    for (int s = 0; s < NS; ++s) {
        int g0 = ip[s * N_PTS];
        int g1 = ip[s * N_PTS + 16];
        #pragma unroll
        for (int h = 0; h < 2; ++h) {
            int ko = s * 64 + (h * 4 + l4) * 8;          // k offset (ushorts)
            int kx = (h * 4 + l4) * 8;
            bf16x8 a0 = *(const bf16x8*)(wp + ko);
            bf16x8 a1 = *(const bf16x8*)(wp + 16 * KTOT + ko);
            bf16x8 b0 = *(const bf16x8*)(xTb + ((size_t)g0 << 6) + kx);
            bf16x8 b1 = *(const bf16x8*)(xTb + ((size_t)g1 << 6) + kx);
            acc[0][0] = __builtin_amdgcn_mfma_f32_16x16x32_bf16(a0, b0, acc[0][0], 0, 0, 0);
            acc[0][1] = __builtin_amdgcn_mfma_f32_16x16x32_bf16(a0, b1, acc[0][1], 0, 0, 0);
            acc[1][0] = __builtin_amdgcn_mfma_f32_16x16x32_bf16(a1, b0, acc[1][0], 0, 0, 0);
            acc[1][1] = __builtin_amdgcn_mfma_f32_16x16x32_bf16(a1, b1, acc[1][1], 0, 0, 0);
        }
    }

    // epilogue: C/D layout col(n)=lane&15, row(o)=l4*4+j
    float* yb = y + (size_t)b * C_OUT * N_PTS;
    #pragma unroll
    for (int fm = 0; fm < 2; ++fm) {
        #pragma unroll
        for (int j = 0; j < 4; ++j) {
            int o = m0 + fm * 16 + l4 * 4 + j;
            float bo = bias[o];
            #pragma unroll
            for (int fn = 0; fn < 2; ++fn) {
                int n = n0 + fn * 16 + l15;
                yb[(size_t)o * N_PTS + n] = acc[fm][fn][j] + bo;
            }
        }
    }
}

extern "C" void kernel_launch(void* const* d_in, const int* in_sizes, int n_in,
                              void* d_out, int out_size, void* d_ws, size_t ws_size,
                              hipStream_t stream) {
    const float* x    = (const float*)d_in[0];   // [4,64,4096]
    const float* pcs  = (const float*)d_in[1];   // [4,3,4096]
    const float* W    = (const float*)d_in[2];   // [128,64,9]
    const float* bias = (const float*)d_in[3];   // [128]
    float* y = (float*)d_out;                    // [4,128,4096]

    int*    idxT = (int*)d_ws;                                   // 589824 B
    float4* pp   = (float4*)((char*)d_ws + 589824);              // 262144 B
    ushort* xT   = (ushort*)((char*)d_ws + 851968);              // 2097152 B
    ushort* Wt   = (ushort*)((char*)d_ws + 2949120);             // 147456 B

    prep_kernel<<<608, 256, 0, stream>>>(W, x, pcs, Wt, xT, pp);
    ballq_kernel<<<B_SZ * N_PTS / 4, 256, 0, stream>>>(pp, idxT);
    // 10x conv: slope instrumentation (idempotent, deterministic).
    // dur_us = base + 10*conv  ->  conv per-launch time from the headline number.
    for (int r = 0; r < 10; ++r)
        conv_kernel<<<dim3(256, 2), 256, 0, stream>>>(xT, Wt, idxT, bias, y);
}

// Round 6
// 26.530 us; speedup vs baseline: 7.8151x; 7.8151x over previous
//
#include <hip/hip_runtime.h>

#define N_PTS 4096
#define B_SZ 4
#define C_IN 64
#define C_OUT 128
#define NS 9
#define KTOT (C_IN * NS)   // 576
#define RAD2 0.04f

typedef __attribute__((ext_vector_type(8))) short bf16x8;
typedef __attribute__((ext_vector_type(4))) float f32x4;

__device__ inline ushort f2bf(float f) {
    union { float f; unsigned u; } v; v.f = f;
    unsigned r = (v.u + 0x7FFF + ((v.u >> 16) & 1)) >> 16;   // RTNE
    return (ushort)r;
}

__device__ inline void gl_lds16(const void* g, void* l) {
    __builtin_amdgcn_global_load_lds(
        (const __attribute__((address_space(1))) unsigned int*)g,
        (__attribute__((address_space(3))) unsigned int*)l, 16, 0, 0);
}

// ---------------- kernel 0: fused prep (wt | xt | pack-pcs), role by blockIdx ----
// Wt is written PRE-SWIZZLED: ushort dst = o*576 + s*64 + ((c8 ^ (o&7))*8) + c&7
// so conv can stage it LINEARLY into LDS and read with the same XOR swizzle.
__global__ void __launch_bounds__(256) prep_kernel(
    const float* __restrict__ W, const float* __restrict__ x,
    const float* __restrict__ pcs,
    ushort* __restrict__ Wt, ushort* __restrict__ xT, float4* __restrict__ pp)
{
    __shared__ ushort tile[64][66];
    const int t = threadIdx.x;
    const int blk = blockIdx.x;
    if (blk < 288) {                       // ---- Wt (swizzled) ----
        int id = blk * 256 + t;
        int o = id / KTOT;
        int r = id - o * KTOT;             // s*64 + c
        int s = r >> 6, c = r & 63;
        int dst = o * KTOT + s * 64 + (((c >> 3) ^ (o & 7)) << 3) + (c & 7);
        Wt[dst] = f2bf(W[o * KTOT + c * NS + s]);
    } else if (blk < 544) {                // ---- xT [b][n][c] bf16 ----
        int r = blk - 288;
        int b = r >> 6;
        int n0 = (r & 63) * 64;
        const float* xb = x + (size_t)b * C_IN * N_PTS;
        #pragma unroll
        for (int i = 0; i < 16; ++i) {
            int flat = i * 256 + t;
            int c = flat >> 6, n = flat & 63;
            tile[c][n] = f2bf(xb[(size_t)c * N_PTS + n0 + n]);
        }
        __syncthreads();
        ushort* xTb = xT + ((size_t)b * N_PTS + n0) * C_IN;
        #pragma unroll
        for (int i = 0; i < 16; ++i) {
            int flat = i * 256 + t;
            int n = flat >> 6, c = flat & 63;
            xTb[(size_t)n * C_IN + c] = tile[c][n];
        }
    } else {                               // ---- pack pcs -> {x,y,z,sq} ----
        int id = (blk - 544) * 256 + t;
        int b = id >> 12, n = id & (N_PTS - 1);
        const float* pb = pcs + (size_t)b * 3 * N_PTS;
        float px = pb[n], py = pb[N_PTS + n], pz = pb[2 * N_PTS + n];
        float sq = __fadd_rn(__fadd_rn(__fmul_rn(px, px), __fmul_rn(py, py)),
                             __fmul_rn(pz, pz));
        pp[id] = make_float4(px, py, pz, sq);
    }
}

// ---------------- kernel 1: ball query (verified) ----------------
__global__ void __launch_bounds__(256) ballq_kernel(const float4* __restrict__ pp,
                                                    int* __restrict__ idxT) {
    int wid = (blockIdx.x * 256 + threadIdx.x) >> 6;
    int lane = threadIdx.x & 63;
    int b = wid >> 12;
    int n = wid & (N_PTS - 1);
    const float4* pb = pp + (size_t)b * N_PTS;
    float4 c = pb[n];
    int* outb = idxT + (size_t)b * NS * N_PTS + n;
    int cnt = 0, first = -1;
    for (int c0 = 0; c0 < N_PTS; c0 += 256) {
        float4 q[4];
        #pragma unroll
        for (int j = 0; j < 4; ++j) q[j] = pb[c0 + j * 64 + lane];
        #pragma unroll
        for (int j = 0; j < 4; ++j) {
            int m = c0 + j * 64 + lane;
            float dot = __fadd_rn(__fadd_rn(__fmul_rn(c.x, q[j].x),
                                            __fmul_rn(c.y, q[j].y)),
                                  __fmul_rn(c.z, q[j].z));
            float d2 = __fsub_rn(__fadd_rn(c.w, q[j].w), __fmul_rn(2.0f, dot));
            bool hit = !(d2 > RAD2);
            unsigned long long mask = __ballot(hit);
            if (mask) {
                if (first < 0) first = c0 + j * 64 + __ffsll(mask) - 1;
                int pre = __popcll(mask & ((1ull << lane) - 1ull));
                if (hit) {
                    int slot = cnt + pre;
                    if (slot < NS) outb[slot * N_PTS] = m;
                }
                cnt += __popcll(mask);
                if (cnt >= NS) break;
            }
        }
        if (cnt >= NS) break;
    }
    if (lane >= cnt && lane < NS) outb[lane * N_PTS] = first;
}

// ---------------- kernel 2: stage-once MFMA GEMM ----------------
// 256 blocks (1/CU), 4 waves. Block: 128(o) x 64(n), two 64-o halves.
// All X rows (576) + one W half staged via global_load_lds (async burst),
// ONE barrier, then pure LDS+MFMA. XOR-swizzled (src-preswizzle + swz read).
__global__ void __launch_bounds__(256) conv_kernel(
    const ushort* __restrict__ xT, const ushort* __restrict__ Wt,
    const int* __restrict__ idxT, const float* __restrict__ bias,
    float* __restrict__ y)
{
    __shared__ __align__(16) ushort Wlds[64 * KTOT];    // 72 KB
    __shared__ __align__(16) ushort Xlds[576 * 64];     // 72 KB

    const int t = threadIdx.x;
    const int lane = t & 63;
    const int wid = t >> 6;          // 0..3
    const int ntile = blockIdx.x;    // 0..63
    const int b = blockIdx.y;        // 0..3
    const int n64 = ntile * 64;
    const int l15 = lane & 15;
    const int l4 = lane >> 4;        // 0..3

    const ushort* xTb = xT + (size_t)b * N_PTS * C_IN;
    const int* idxTb = idxT + (size_t)b * NS * N_PTS;

    // ---- neighbor indices for this wave's 144 X rows (row = s*64 + nloc) ----
    const int rb = wid * 144;
    int g[18];
    #pragma unroll
    for (int j = 0; j < 18; ++j) {
        int r = rb + j * 8 + (lane >> 3);
        g[j] = idxTb[((r >> 6) << 12) + n64 + (r & 63)];
    }

    // ---- stage W half0 (linear; source pre-swizzled by prep) ----
    {
        const ushort* wsrc = Wt + wid * 9216;           // 18 KB per wave
        #pragma unroll
        for (int j = 0; j < 18; ++j)
            gl_lds16(wsrc + j * 512 + lane * 8,
                     &Wlds[wid * 9216 + j * 512 + lane * 8]);
    }
    // ---- stage X: gathered rows, per-lane pre-swizzled source chunk ----
    {
        const int sx = (((lane & 7) ^ (lane >> 3)) << 3);   // ushort offset in row
        #pragma unroll
        for (int j = 0; j < 18; ++j)
            gl_lds16(xTb + ((size_t)g[j] << 6) + sx,
                     &Xlds[(rb + j * 8) * 64 + lane * 8]);
    }
    __syncthreads();   // drains vmcnt (incl. global_load_lds) + barrier

    const int m0 = (wid & 1) * 32;       // wave o-base within half
    const int n0 = (wid >> 1) * 32;      // wave n-base within tile
    const int ra0 = m0 + l15;            // A rows (swizzle key = row&7 = l15&7)
    const int rb0 = n0 + l15;            // B rows
    const int swA = (ra0 & 7);
    const int swB = (rb0 & 7);
    float* yb = y + (size_t)b * C_OUT * N_PTS + n64;

    #pragma unroll
    for (int half = 0; half < 2; ++half) {
        f32x4 acc[2][2];
        #pragma unroll
        for (int i = 0; i < 2; ++i)
            #pragma unroll
            for (int j = 0; j < 2; ++j)
                acc[i][j] = (f32x4){0.f, 0.f, 0.f, 0.f};

        #pragma unroll
        for (int s = 0; s < NS; ++s) {
            #pragma unroll
            for (int hh = 0; hh < 2; ++hh) {
                int d = hh * 4 + l4;
                bf16x8 a0 = *(const bf16x8*)&Wlds[ra0 * KTOT + s * 64 + ((d ^ swA) << 3)];
                bf16x8 a1 = *(const bf16x8*)&Wlds[(ra0 + 16) * KTOT + s * 64 + ((d ^ swA) << 3)];
                bf16x8 b0 = *(const bf16x8*)&Xlds[(s * 64 + rb0) * 64 + ((d ^ swB) << 3)];
                bf16x8 b1 = *(const bf16x8*)&Xlds[(s * 64 + rb0 + 16) * 64 + ((d ^ swB) << 3)];
                acc[0][0] = __builtin_amdgcn_mfma_f32_16x16x32_bf16(a0, b0, acc[0][0], 0, 0, 0);
                acc[0][1] = __builtin_amdgcn_mfma_f32_16x16x32_bf16(a0, b1, acc[0][1], 0, 0, 0);
                acc[1][0] = __builtin_amdgcn_mfma_f32_16x16x32_bf16(a1, b0, acc[1][0], 0, 0, 0);
                acc[1][1] = __builtin_amdgcn_mfma_f32_16x16x32_bf16(a1, b1, acc[1][1], 0, 0, 0);
            }
        }

        // epilogue: C/D col(n)=lane&15, row(o)=l4*4+j
        #pragma unroll
        for (int fm = 0; fm < 2; ++fm) {
            #pragma unroll
            for (int j = 0; j < 4; ++j) {
                int o = half * 64 + m0 + fm * 16 + l4 * 4 + j;
                float bo = bias[o];
                #pragma unroll
                for (int fn = 0; fn < 2; ++fn) {
                    int n = n0 + fn * 16 + l15;
                    yb[(size_t)o * N_PTS + n] = acc[fm][fn][j] + bo;
                }
            }
        }

        // re-stage W half1 over the same LDS (X untouched)
        if (half == 0) {
            __syncthreads();   // everyone done reading W half0
            const ushort* wsrc = Wt + 36864 + wid * 9216;
            #pragma unroll
            for (int j = 0; j < 18; ++j)
                gl_lds16(wsrc + j * 512 + lane * 8,
                         &Wlds[wid * 9216 + j * 512 + lane * 8]);
            __syncthreads();   // drain + barrier
        }
    }
}

extern "C" void kernel_launch(void* const* d_in, const int* in_sizes, int n_in,
                              void* d_out, int out_size, void* d_ws, size_t ws_size,
                              hipStream_t stream) {
    const float* x    = (const float*)d_in[0];   // [4,64,4096]
    const float* pcs  = (const float*)d_in[1];   // [4,3,4096]
    const float* W    = (const float*)d_in[2];   // [128,64,9]
    const float* bias = (const float*)d_in[3];   // [128]
    float* y = (float*)d_out;                    // [4,128,4096]

    int*    idxT = (int*)d_ws;                                   // 589824 B
    float4* pp   = (float4*)((char*)d_ws + 589824);              // 262144 B
    ushort* xT   = (ushort*)((char*)d_ws + 851968);              // 2097152 B
    ushort* Wt   = (ushort*)((char*)d_ws + 2949120);             // 147456 B

    prep_kernel<<<608, 256, 0, stream>>>(W, x, pcs, Wt, xT, pp);
    ballq_kernel<<<B_SZ * N_PTS / 4, 256, 0, stream>>>(pp, idxT);
    conv_kernel<<<dim3(64, B_SZ), 256, 0, stream>>>(xT, Wt, idxT, bias, y);
}